// Round 2
// baseline (1773.598 us; speedup 1.0000x reference)
//
#include <hip/hip_runtime.h>
#include <math.h>

// Problem constants (from reference)
#define NB 8
#define NS 2048
#define ND 1024
#define NK 4096           // codebook entries
#define NM (NB * NS)      // 16384 tokens

// GEMM tiling
#define BM 128
#define BN 128
#define BK 16
#define NTILES (NK / BN)  // 32

struct Top2 { float m1; int i1; float m2; int i2; };

__device__ __forceinline__ void top2_push(float m, int i,
                                          float& m1, int& i1, float& m2, int& i2) {
  // keep two smallest; tie-break toward lower index (matches np.argmin first-min)
  if (m < m1 || (m == m1 && i < i1)) { m2 = m1; i2 = i1; m1 = m; i1 = i; }
  else if (m < m2 || (m == m2 && i < i2)) { m2 = m; i2 = i; }
}

// ---------------------------------------------------------------------------
// Kernel 1: codebook squared norms (fp64 accumulate, stored fp32)
// ---------------------------------------------------------------------------
__global__ void vq_cnorm(const float* __restrict__ cb, float* __restrict__ cnorm) {
  const int lane = threadIdx.x & 63;
  const int code = blockIdx.x * 4 + (threadIdx.x >> 6);
  const float* c = cb + (size_t)code * ND;
  double s = 0.0;
#pragma unroll
  for (int j = 0; j < ND / 64; ++j) {
    double v = (double)c[lane + 64 * j];
    s = fma(v, v, s);
  }
#pragma unroll
  for (int off = 32; off > 0; off >>= 1) s += __shfl_down(s, off, 64);
  if (lane == 0) cnorm[code] = (float)s;
}

// ---------------------------------------------------------------------------
// Kernel 2: fp32 tiled score GEMM  score = ||c||^2 - 2 * x.c
// each block: BM tokens x BN codes; per-token top-2 partial per N-tile
// ---------------------------------------------------------------------------
__global__ void vq_dist(const float* __restrict__ x, const float* __restrict__ cb,
                        const float* __restrict__ cnorm, Top2* __restrict__ part) {
  // LDS: staging tiles (transposed) unioned with epilogue top2 scratch
  __shared__ __align__(16) char smem_raw[34816];
  float (*As)[BM + 4] = reinterpret_cast<float (*)[BM + 4]>(smem_raw);
  float (*Bs)[BN + 4] = reinterpret_cast<float (*)[BN + 4]>(
      smem_raw + sizeof(float) * BK * (BM + 4));
  Top2 (*Ep)[17] = reinterpret_cast<Top2 (*)[17]>(smem_raw);

  const int tid = threadIdx.x;
  const int m0 = blockIdx.y * BM;
  const int n0 = blockIdx.x * BN;
  const int ty = tid >> 4;        // 0..15  (token group)
  const int tx = tid & 15;        // 0..15  (code group)
  const int lrow = tid >> 2;      // 0..63  (staging row)
  const int lk4 = (tid & 3) << 2; // 0,4,8,12 (staging k)

  float acc[8][8];
#pragma unroll
  for (int i = 0; i < 8; ++i)
#pragma unroll
    for (int j = 0; j < 8; ++j) acc[i][j] = 0.f;

  for (int k0 = 0; k0 < ND; k0 += BK) {
#pragma unroll
    for (int h = 0; h < 2; ++h) {
      const int row = lrow + h * 64;
      float4 va = *reinterpret_cast<const float4*>(
          x + (size_t)(m0 + row) * ND + k0 + lk4);
      As[lk4 + 0][row] = va.x; As[lk4 + 1][row] = va.y;
      As[lk4 + 2][row] = va.z; As[lk4 + 3][row] = va.w;
      float4 vb = *reinterpret_cast<const float4*>(
          cb + (size_t)(n0 + row) * ND + k0 + lk4);
      Bs[lk4 + 0][row] = vb.x; Bs[lk4 + 1][row] = vb.y;
      Bs[lk4 + 2][row] = vb.z; Bs[lk4 + 3][row] = vb.w;
    }
    __syncthreads();
#pragma unroll
    for (int kk = 0; kk < BK; ++kk) {
      float a[8], b[8];
#pragma unroll
      for (int i = 0; i < 8; ++i) a[i] = As[kk][ty * 8 + i];
#pragma unroll
      for (int j = 0; j < 8; ++j) b[j] = Bs[kk][tx * 8 + j];
#pragma unroll
      for (int i = 0; i < 8; ++i)
#pragma unroll
        for (int j = 0; j < 8; ++j) acc[i][j] = fmaf(a[i], b[j], acc[i][j]);
    }
    __syncthreads();
  }

  // epilogue: score = cnorm - 2*acc ; per-thread top2 over its 8 codes
  float cn[8];
#pragma unroll
  for (int j = 0; j < 8; ++j) cn[j] = cnorm[n0 + tx * 8 + j];

#pragma unroll
  for (int i = 0; i < 8; ++i) {
    float m1 = INFINITY, m2 = INFINITY; int i1 = 0x7fffffff, i2 = 0x7fffffff;
#pragma unroll
    for (int j = 0; j < 8; ++j) {
      float d = fmaf(-2.f, acc[i][j], cn[j]);
      top2_push(d, n0 + tx * 8 + j, m1, i1, m2, i2);
    }
    Top2 e; e.m1 = m1; e.i1 = i1; e.m2 = m2; e.i2 = i2;
    Ep[ty * 8 + i][tx] = e;
  }
  __syncthreads();

  if (tid < BM) {
    float m1 = INFINITY, m2 = INFINITY; int i1 = 0x7fffffff, i2 = 0x7fffffff;
#pragma unroll
    for (int t = 0; t < 16; ++t) {
      Top2 e = Ep[tid][t];
      top2_push(e.m1, e.i1, m1, i1, m2, i2);
      top2_push(e.m2, e.i2, m1, i1, m2, i2);
    }
    Top2 r; r.m1 = m1; r.i1 = i1; r.m2 = m2; r.i2 = i2;
    part[(size_t)(m0 + tid) * NTILES + blockIdx.x] = r;
  }
}

// ---------------------------------------------------------------------------
// Kernel 3: per-token: merge 32 partials -> top2; fp64-exact refine of the two
// candidates; gather winning code + positional encoding -> out
// ---------------------------------------------------------------------------
__global__ void vq_finalize(const float* __restrict__ x, const float* __restrict__ cb,
                            const Top2* __restrict__ part, float* __restrict__ out) {
  const int t = blockIdx.x;          // token
  const int s = t & (NS - 1);        // sequence position
  const int tid = threadIdx.x;
  const int lane = tid & 63;
  const int wave = tid >> 6;

  __shared__ int cand[2];
  __shared__ double dred[4][2];
  __shared__ int sel_s;

  if (wave == 0) {
    float m1 = INFINITY, m2 = INFINITY; int i1 = 0x7fffffff, i2 = 0x7fffffff;
    if (lane < NTILES) {
      Top2 e = part[(size_t)t * NTILES + lane];
      m1 = e.m1; i1 = e.i1; m2 = e.m2; i2 = e.i2;
    }
#pragma unroll
    for (int off = 16; off > 0; off >>= 1) {
      float om1 = __shfl_down(m1, off, 64); int oi1 = __shfl_down(i1, off, 64);
      float om2 = __shfl_down(m2, off, 64); int oi2 = __shfl_down(i2, off, 64);
      top2_push(om1, oi1, m1, i1, m2, i2);
      top2_push(om2, oi2, m1, i1, m2, i2);
    }
    if (lane == 0) { cand[0] = i1; cand[1] = i2; }
  }
  __syncthreads();
  const int i1 = cand[0], i2 = cand[1];

  // exact squared distances in fp64 for the two candidates
  const float* xt = x + (size_t)t * ND;
  const float* c1 = cb + (size_t)i1 * ND;
  const float* c2 = cb + (size_t)i2 * ND;
  double d1 = 0.0, d2 = 0.0;
#pragma unroll
  for (int r = 0; r < ND / 256; ++r) {
    int j = tid + 256 * r;
    double xv = (double)xt[j];
    double a = xv - (double)c1[j];
    double b = xv - (double)c2[j];
    d1 = fma(a, a, d1);
    d2 = fma(b, b, d2);
  }
#pragma unroll
  for (int off = 32; off > 0; off >>= 1) {
    d1 += __shfl_down(d1, off, 64);
    d2 += __shfl_down(d2, off, 64);
  }
  if (lane == 0) { dred[wave][0] = d1; dred[wave][1] = d2; }
  __syncthreads();
  if (tid == 0) {
    double D1 = 0.0, D2 = 0.0;
#pragma unroll
    for (int w = 0; w < 4; ++w) { D1 += dred[w][0]; D2 += dred[w][1]; }
    sel_s = (D2 < D1 || (D2 == D1 && i2 < i1)) ? i2 : i1;
  }
  __syncthreads();
  const int sel = sel_s;

  // gather + positional encoding
  const float coef = (float)(9.210340371976184 / 1024.0);  // ln(10000)/D
  const float* cs = cb + (size_t)sel * ND;
  float* ot = out + (size_t)t * ND;
  const float sf = (float)s;
#pragma unroll
  for (int r = 0; r < ND / 256; ++r) {
    int j = tid + 256 * r;
    int iv = j & ~1;
    float div = expf(-(float)iv * coef);
    float ang = sf * div;
    float pe = (j & 1) ? cosf(ang) : sinf(ang);
    ot[j] = cs[j] + pe;
  }
}

// ---------------------------------------------------------------------------
extern "C" void kernel_launch(void* const* d_in, const int* in_sizes, int n_in,
                              void* d_out, int out_size, void* d_ws, size_t ws_size,
                              hipStream_t stream) {
  const float* x = (const float*)d_in[0];     // [8,2048,1024] fp32
  const float* cb = (const float*)d_in[1];    // [4096,1024] fp32
  float* out = (float*)d_out;                 // [8,2048,1024] fp32

  // workspace: [0,16KB) cnorm ; [16KB, 16KB+8MB) Top2 partials
  float* cnorm = (float*)d_ws;
  Top2* part = (Top2*)((char*)d_ws + 16384);

  vq_cnorm<<<NK / 4, 256, 0, stream>>>(cb, cnorm);
  dim3 g2(NTILES, NM / BM);  // (32, 128)
  vq_dist<<<g2, 256, 0, stream>>>(x, cb, cnorm, part);
  vq_finalize<<<NM, 256, 0, stream>>>(x, cb, part, out);
}

// Round 6
// 925.487 us; speedup vs baseline: 1.9164x; 1.9164x over previous
//
#include <hip/hip_runtime.h>
#include <math.h>

// Problem constants
#define NB 8
#define NS 2048
#define ND 1024
#define NK 4096
#define NM (NB * NS)      // 16384 tokens

// GEMM tiling (m97 structure: 128x128 tile, 4 waves, 4x4 16x16x32 frags/wave)
#define BM 128
#define BN 128
#define BK 32
#define NTILES (NK / BN)  // 32

typedef __attribute__((ext_vector_type(8))) short bf8_t;     // bf16x8 MFMA operand
typedef __attribute__((ext_vector_type(4))) float f4_t;      // fp32x4 accum
typedef __attribute__((ext_vector_type(8))) unsigned short us8_t;

#define GLOBAL_AS(p) ((const __attribute__((address_space(1))) void*)(p))
#define LDS_AS(p)    ((__attribute__((address_space(3))) void*)(p))

struct Top2 { float m1; int i1; float m2; int i2; };

__device__ __forceinline__ void top2_push(float m, int i,
                                          float& m1, int& i1, float& m2, int& i2) {
  if (m < m1 || (m == m1 && i < i1)) { m2 = m1; i2 = i1; m1 = m; i1 = i; }
  else if (m < m2 || (m == m2 && i < i2)) { m2 = m; i2 = i; }
}

__device__ __forceinline__ unsigned short f2bf(float f) {
  unsigned u = __float_as_uint(f);
  u += 0x7fffu + ((u >> 16) & 1u);   // RNE (inputs are finite normals)
  return (unsigned short)(u >> 16);
}

// ---------------------------------------------------------------------------
// Kernel 0: fp32 -> bf16 conversion of x and codebook into workspace
// ---------------------------------------------------------------------------
__global__ void vq_convert(const float* __restrict__ x, const float* __restrict__ cb,
                           unsigned short* __restrict__ xb, unsigned short* __restrict__ cbb) {
  const int xg = NM * ND / 8;               // 2,097,152 groups of 8
  const int total = xg + NK * ND / 8;       // + 524,288
  for (int g = blockIdx.x * blockDim.x + threadIdx.x; g < total;
       g += gridDim.x * blockDim.x) {
    const float* src; unsigned short* dst; size_t off;
    if (g < xg) { src = x; dst = xb; off = (size_t)g * 8; }
    else        { src = cb; dst = cbb; off = (size_t)(g - xg) * 8; }
    float4 a = *reinterpret_cast<const float4*>(src + off);
    float4 b = *reinterpret_cast<const float4*>(src + off + 4);
    us8_t o;
    o[0] = f2bf(a.x); o[1] = f2bf(a.y); o[2] = f2bf(a.z); o[3] = f2bf(a.w);
    o[4] = f2bf(b.x); o[5] = f2bf(b.y); o[6] = f2bf(b.z); o[7] = f2bf(b.w);
    *reinterpret_cast<us8_t*>(dst + off) = o;
  }
}

// ---------------------------------------------------------------------------
// Kernel 1: codebook squared norms (fp64 accumulate from fp32 source, exact)
// ---------------------------------------------------------------------------
__global__ void vq_cnorm(const float* __restrict__ cb, float* __restrict__ cnorm) {
  const int lane = threadIdx.x & 63;
  const int code = blockIdx.x * 4 + (threadIdx.x >> 6);
  const float* c = cb + (size_t)code * ND;
  double s = 0.0;
#pragma unroll
  for (int j = 0; j < ND / 64; ++j) {
    double v = (double)c[lane + 64 * j];
    s = fma(v, v, s);
  }
#pragma unroll
  for (int off = 32; off > 0; off >>= 1) s += __shfl_down(s, off, 64);
  if (lane == 0) cnorm[code] = (float)s;
}

// ---------------------------------------------------------------------------
// Kernel 2: bf16 MFMA score GEMM  score = ||c||^2 - 2 * x.c
// m97 structure: 128x128 tile, BK=32, global_load_lds(16B), 2 barriers/K-step.
// Epilogue: per-token top-2 within the 128-col tile -> part[]
// ---------------------------------------------------------------------------
__global__ void __launch_bounds__(256)
vq_dist_bf16(const unsigned short* __restrict__ xb, const unsigned short* __restrict__ cbb,
             const float* __restrict__ cnorm, Top2* __restrict__ part) {
  // LDS: As[128][32] bf16 (8KB) + Bs[128][32] bf16 (8KB); epilogue aliases As
  __shared__ __align__(16) char smem[16384];
  Top2 (*Ep)[2] = reinterpret_cast<Top2 (*)[2]>(smem);

  const int tid = threadIdx.x;
  const int lane = tid & 63;
  const int wid = tid >> 6;          // 0..3
  const int wr = wid >> 1, wc = wid & 1;
  const int lo = lane & 15, hi = lane >> 4;
  const int m0 = blockIdx.y * BM;
  const int n0 = blockIdx.x * BN;

  // staging: wave wid owns rows [wid*32, wid*32+32) of each tile; 2 issues each
  const unsigned short* aSrc = xb + (size_t)(m0 + wid * 32 + (lane >> 2)) * ND + (lane & 3) * 8;
  const unsigned short* bSrc = cbb + (size_t)(n0 + wid * 32 + (lane >> 2)) * ND + (lane & 3) * 8;
  char* aDst = smem + wid * 32 * 64;          // wave-uniform
  char* bDst = smem + 8192 + wid * 32 * 64;

  // fragment read bases (row-major [row][32] bf16, 64B row stride)
  const char* aRd = smem + (wr * 64 + lo) * 64 + hi * 16;
  const char* bRd = smem + 8192 + (wc * 64 + lo) * 64 + hi * 16;

  f4_t acc[4][4];
#pragma unroll
  for (int m = 0; m < 4; ++m)
#pragma unroll
    for (int n = 0; n < 4; ++n) acc[m][n] = (f4_t)0.f;

  for (int k0 = 0; k0 < ND; k0 += BK) {
    __builtin_amdgcn_global_load_lds(GLOBAL_AS(aSrc + k0), LDS_AS(aDst), 16, 0, 0);
    __builtin_amdgcn_global_load_lds(GLOBAL_AS(aSrc + k0 + 16 * ND), LDS_AS(aDst + 1024), 16, 0, 0);
    __builtin_amdgcn_global_load_lds(GLOBAL_AS(bSrc + k0), LDS_AS(bDst), 16, 0, 0);
    __builtin_amdgcn_global_load_lds(GLOBAL_AS(bSrc + k0 + 16 * ND), LDS_AS(bDst + 1024), 16, 0, 0);
    __syncthreads();

    bf8_t af[4], bfr[4];
#pragma unroll
    for (int m = 0; m < 4; ++m) af[m] = *reinterpret_cast<const bf8_t*>(aRd + m * 1024);
#pragma unroll
    for (int n = 0; n < 4; ++n) bfr[n] = *reinterpret_cast<const bf8_t*>(bRd + n * 1024);
#pragma unroll
    for (int m = 0; m < 4; ++m)
#pragma unroll
      for (int n = 0; n < 4; ++n)
        acc[m][n] = __builtin_amdgcn_mfma_f32_16x16x32_bf16(af[m], bfr[n], acc[m][n], 0, 0, 0);
    __syncthreads();
  }

  // epilogue: score = cnorm - 2*acc; C/D layout: col = lane&15, row = hi*4+j
  float cn[4];
#pragma unroll
  for (int n = 0; n < 4; ++n) cn[n] = cnorm[n0 + wc * 64 + n * 16 + lo];

#pragma unroll
  for (int m = 0; m < 4; ++m) {
#pragma unroll
    for (int j = 0; j < 4; ++j) {
      float m1 = INFINITY, m2 = INFINITY; int i1 = 0x7fffffff, i2 = 0x7fffffff;
#pragma unroll
      for (int n = 0; n < 4; ++n) {
        float s = fmaf(-2.f, acc[m][n][j], cn[n]);
        top2_push(s, n0 + wc * 64 + n * 16 + lo, m1, i1, m2, i2);
      }
      // reduce across the 16 lanes sharing this row (lo = 0..15)
#pragma unroll
      for (int mask = 1; mask <= 8; mask <<= 1) {
        float om1 = __shfl_xor(m1, mask, 64); int oi1 = __shfl_xor(i1, mask, 64);
        float om2 = __shfl_xor(m2, mask, 64); int oi2 = __shfl_xor(i2, mask, 64);
        top2_push(om1, oi1, m1, i1, m2, i2);
        top2_push(om2, oi2, m1, i1, m2, i2);
      }
      if (lo == 0) {
        int row = wr * 64 + m * 16 + hi * 4 + j;
        Top2 e; e.m1 = m1; e.i1 = i1; e.m2 = m2; e.i2 = i2;
        Ep[row][wc] = e;
      }
    }
  }
  __syncthreads();

  if (tid < BM) {
    Top2 a = Ep[tid][0], b = Ep[tid][1];
    float m1 = a.m1, m2 = a.m2; int i1 = a.i1, i2 = a.i2;
    top2_push(b.m1, b.i1, m1, i1, m2, i2);
    top2_push(b.m2, b.i2, m1, i1, m2, i2);
    Top2 r; r.m1 = m1; r.i1 = i1; r.m2 = m2; r.i2 = i2;
    part[(size_t)(m0 + tid) * NTILES + blockIdx.x] = r;
  }
}

// ---------------------------------------------------------------------------
// Kernel 3: merge 32 per-tile top-2 -> computed top-4; fp64-exact refine;
// gather winning code + positional encoding
// ---------------------------------------------------------------------------
__device__ __forceinline__ void ins4(float m, int i, float v[4], int ix[4]) {
  if (!(m < v[3] || (m == v[3] && i < ix[3]))) return;
  v[3] = m; ix[3] = i;
  if (v[3] < v[2] || (v[3] == v[2] && ix[3] < ix[2])) {
    float tv = v[2]; v[2] = v[3]; v[3] = tv; int ti = ix[2]; ix[2] = ix[3]; ix[3] = ti;
  }
  if (v[2] < v[1] || (v[2] == v[1] && ix[2] < ix[1])) {
    float tv = v[1]; v[1] = v[2]; v[2] = tv; int ti = ix[1]; ix[1] = ix[2]; ix[2] = ti;
  }
  if (v[1] < v[0] || (v[1] == v[0] && ix[1] < ix[0])) {
    float tv = v[0]; v[0] = v[1]; v[1] = tv; int ti = ix[0]; ix[0] = ix[1]; ix[1] = ti;
  }
}

__global__ void vq_finalize(const float* __restrict__ x, const float* __restrict__ cb,
                            const Top2* __restrict__ part, float* __restrict__ out) {
  const int t = blockIdx.x;
  const int s = t & (NS - 1);
  const int tid = threadIdx.x;
  const int lane = tid & 63;
  const int wav = tid >> 6;

  __shared__ int candS[4];
  __shared__ double dS[4];
  __shared__ int selS;

  if (wav == 0) {
    float v[4] = {INFINITY, INFINITY, INFINITY, INFINITY};
    int ix[4] = {0x7fffffff, 0x7fffffff, 0x7fffffff, 0x7fffffff};
    if (lane < NTILES) {
      Top2 e = part[(size_t)t * NTILES + lane];
      v[0] = e.m1; ix[0] = e.i1; v[1] = e.m2; ix[1] = e.i2;
    }
#pragma unroll
    for (int mask = 1; mask <= 16; mask <<= 1) {
      float ov[4]; int oi[4];
#pragma unroll
      for (int p = 0; p < 4; ++p) { ov[p] = __shfl_xor(v[p], mask, 64); oi[p] = __shfl_xor(ix[p], mask, 64); }
#pragma unroll
      for (int p = 0; p < 4; ++p) ins4(ov[p], oi[p], v, ix);
    }
    if (lane < 4) candS[lane] = ix[lane];
  }
  __syncthreads();

  // fp64-exact refine: wave w -> candidate w
  const int ci = candS[wav];
  const float* xt = x + (size_t)t * ND;
  const float* c = cb + (size_t)ci * ND;
  double d = 0.0;
#pragma unroll
  for (int r = 0; r < ND / 64; ++r) {
    int j = lane + 64 * r;
    double a = (double)xt[j] - (double)c[j];
    d = fma(a, a, d);
  }
#pragma unroll
  for (int off = 32; off > 0; off >>= 1) d += __shfl_down(d, off, 64);
  if (lane == 0) dS[wav] = d;
  __syncthreads();

  if (tid == 0) {
    double bd = dS[0]; int bi = candS[0];
#pragma unroll
    for (int w = 1; w < 4; ++w) {
      if (dS[w] < bd || (dS[w] == bd && candS[w] < bi)) { bd = dS[w]; bi = candS[w]; }
    }
    selS = bi;
  }
  __syncthreads();
  const int sel = selS;

  // gather + positional encoding
  const float coef = (float)(9.210340371976184 / 1024.0);  // ln(10000)/D
  const float* cs = cb + (size_t)sel * ND;
  float* ot = out + (size_t)t * ND;
  const float sf = (float)s;
#pragma unroll
  for (int r = 0; r < ND / 256; ++r) {
    int j = tid + 256 * r;
    int iv = j & ~1;
    float div = expf(-(float)iv * coef);
    float ang = sf * div;
    float pe = (j & 1) ? cosf(ang) : sinf(ang);
    ot[j] = cs[j] + pe;
  }
}

// ---------------------------------------------------------------------------
extern "C" void kernel_launch(void* const* d_in, const int* in_sizes, int n_in,
                              void* d_out, int out_size, void* d_ws, size_t ws_size,
                              hipStream_t stream) {
  const float* x = (const float*)d_in[0];     // [8,2048,1024] fp32
  const float* cb = (const float*)d_in[1];    // [4096,1024] fp32
  float* out = (float*)d_out;

  // workspace layout:
  // [0, 32MB)            x_bf16   (16,777,216 ushort)
  // [32MB, 40MB)         cb_bf16  (4,194,304 ushort)
  // [40MB, +16KB)        cnorm
  // [40MB+16KB, +8MB)    Top2 partials
  unsigned short* xb = (unsigned short*)d_ws;
  unsigned short* cbb = (unsigned short*)((char*)d_ws + (size_t)NM * ND * 2);
  float* cnorm = (float*)((char*)d_ws + (size_t)NM * ND * 2 + (size_t)NK * ND * 2);
  Top2* part = (Top2*)((char*)cnorm + 16384);

  vq_convert<<<2048, 256, 0, stream>>>(x, cb, xb, cbb);
  vq_cnorm<<<NK / 4, 256, 0, stream>>>(cb, cnorm);
  dim3 g2(NTILES, NM / BM);  // (32, 128)
  vq_dist_bf16<<<g2, 256, 0, stream>>>(xb, cbb, cnorm, part);
  vq_finalize<<<NM, 256, 0, stream>>>(x, cb, part, out);
}

// Round 7
// 907.132 us; speedup vs baseline: 1.9552x; 1.0202x over previous
//
#include <hip/hip_runtime.h>
#include <math.h>

// Problem constants
#define NB 8
#define NS 2048
#define ND 1024
#define NK 4096
#define NM (NB * NS)      // 16384 tokens

// GEMM tiling: 128x128 tile, 4 waves, 4x4 16x16x32 frags/wave, BK=32,
// depth-2 prefetch pipeline with counted vmcnt (T3+T4 minimum form).
#define BM 128
#define BN 128
#define BK 32
#define NT (ND / BK)      // 32 K-tiles
#define NTILES (NK / BN)  // 32

typedef __attribute__((ext_vector_type(8))) short bf8_t;     // bf16x8 MFMA operand
typedef __attribute__((ext_vector_type(4))) float f4_t;      // fp32x4 accum
typedef __attribute__((ext_vector_type(8))) unsigned short us8_t;

#define GLOBAL_AS(p) ((const __attribute__((address_space(1))) void*)(p))
#define LDS_AS(p)    ((__attribute__((address_space(3))) void*)(p))

struct Top2 { float m1; int i1; float m2; int i2; };

__device__ __forceinline__ void top2_push(float m, int i,
                                          float& m1, int& i1, float& m2, int& i2) {
  if (m < m1 || (m == m1 && i < i1)) { m2 = m1; i2 = i1; m1 = m; i1 = i; }
  else if (m < m2 || (m == m2 && i < i2)) { m2 = m; i2 = i; }
}

__device__ __forceinline__ unsigned short f2bf(float f) {
  unsigned u = __float_as_uint(f);
  u += 0x7fffu + ((u >> 16) & 1u);   // RNE (inputs are finite normals)
  return (unsigned short)(u >> 16);
}

// ---------------------------------------------------------------------------
// Kernel 0: fp32 -> bf16 conversion of x and codebook into workspace
// ---------------------------------------------------------------------------
__global__ void vq_convert(const float* __restrict__ x, const float* __restrict__ cb,
                           unsigned short* __restrict__ xb, unsigned short* __restrict__ cbb) {
  const int xg = NM * ND / 8;               // 2,097,152 groups of 8
  const int total = xg + NK * ND / 8;       // + 524,288
  for (int g = blockIdx.x * blockDim.x + threadIdx.x; g < total;
       g += gridDim.x * blockDim.x) {
    const float* src; unsigned short* dst; size_t off;
    if (g < xg) { src = x; dst = xb; off = (size_t)g * 8; }
    else        { src = cb; dst = cbb; off = (size_t)(g - xg) * 8; }
    float4 a = *reinterpret_cast<const float4*>(src + off);
    float4 b = *reinterpret_cast<const float4*>(src + off + 4);
    us8_t o;
    o[0] = f2bf(a.x); o[1] = f2bf(a.y); o[2] = f2bf(a.z); o[3] = f2bf(a.w);
    o[4] = f2bf(b.x); o[5] = f2bf(b.y); o[6] = f2bf(b.z); o[7] = f2bf(b.w);
    *reinterpret_cast<us8_t*>(dst + off) = o;
  }
}

// ---------------------------------------------------------------------------
// Kernel 1: codebook squared norms (fp64 accumulate from fp32 source, exact)
// ---------------------------------------------------------------------------
__global__ void vq_cnorm(const float* __restrict__ cb, float* __restrict__ cnorm) {
  const int lane = threadIdx.x & 63;
  const int code = blockIdx.x * 4 + (threadIdx.x >> 6);
  const float* c = cb + (size_t)code * ND;
  double s = 0.0;
#pragma unroll
  for (int j = 0; j < ND / 64; ++j) {
    double v = (double)c[lane + 64 * j];
    s = fma(v, v, s);
  }
#pragma unroll
  for (int off = 32; off > 0; off >>= 1) s += __shfl_down(s, off, 64);
  if (lane == 0) cnorm[code] = (float)s;
}

// ---------------------------------------------------------------------------
// Kernel 2: bf16 MFMA score GEMM  score = ||c||^2 - 2 * x.c
// Depth-2 prefetch: 3 LDS buffers; per K-step issue tile t+2, compute tile t,
// then s_waitcnt vmcnt(4) (tile t+1's 4 oldest loads done; t+2's stay in
// flight across the barrier) + raw s_barrier. Never drains vmcnt to 0 in the
// main loop (T4). Epilogue: per-token top-2 within the 128-col tile.
// ---------------------------------------------------------------------------
__global__ void __launch_bounds__(256)
vq_dist_bf16(const unsigned short* __restrict__ xb, const unsigned short* __restrict__ cbb,
             const float* __restrict__ cnorm, Top2* __restrict__ part) {
  // 3 buffers x (A 8KB + B 8KB) = 48KB; epilogue Top2 scratch aliases buf0
  __shared__ __align__(16) char smem[49152];
  Top2 (*Ep)[2] = reinterpret_cast<Top2 (*)[2]>(smem);

  const int tid = threadIdx.x;
  const int lane = tid & 63;
  const int wid = tid >> 6;          // 0..3
  const int wr = wid >> 1, wc = wid & 1;
  const int lo = lane & 15, hi = lane >> 4;
  const int m0 = blockIdx.y * BM;
  const int n0 = blockIdx.x * BN;

  // staging: wave wid owns rows [wid*32, wid*32+32); 2 issues per operand.
  // lane l covers row l>>2, 16B chunk l&3; LDS dest linear (wave-uniform base).
  const unsigned short* aSrc = xb + (size_t)(m0 + wid * 32 + (lane >> 2)) * ND + (lane & 3) * 8;
  const unsigned short* bSrc = cbb + (size_t)(n0 + wid * 32 + (lane >> 2)) * ND + (lane & 3) * 8;

#define STAGE(buf, tile) do {                                                        \
    char* aD_ = smem + (buf) * 16384 + wid * 2048;                                   \
    char* bD_ = smem + (buf) * 16384 + 8192 + wid * 2048;                            \
    const int k0_ = (tile) * BK;                                                     \
    __builtin_amdgcn_global_load_lds(GLOBAL_AS(aSrc + k0_), LDS_AS(aD_), 16, 0, 0);  \
    __builtin_amdgcn_global_load_lds(GLOBAL_AS(aSrc + k0_ + 16 * ND), LDS_AS(aD_ + 1024), 16, 0, 0); \
    __builtin_amdgcn_global_load_lds(GLOBAL_AS(bSrc + k0_), LDS_AS(bD_), 16, 0, 0);  \
    __builtin_amdgcn_global_load_lds(GLOBAL_AS(bSrc + k0_ + 16 * ND), LDS_AS(bD_ + 1024), 16, 0, 0); \
  } while (0)

  f4_t acc[4][4];
#pragma unroll
  for (int m = 0; m < 4; ++m)
#pragma unroll
    for (int n = 0; n < 4; ++n) acc[m][n] = (f4_t)0.f;

  // prologue: tiles 0 and 1 in flight; wait for tile 0 (oldest 4 of 8)
  STAGE(0, 0);
  STAGE(1, 1);
  asm volatile("s_waitcnt vmcnt(4)" ::: "memory");
  __builtin_amdgcn_s_barrier();

  for (int t = 0; t < NT; ++t) {
    const int cur = t % 3;
    if (t + 2 < NT) STAGE((t + 2) % 3, t + 2);

    const char* aRd = smem + cur * 16384 + (wr * 64 + lo) * 64 + hi * 16;
    const char* bRd = smem + cur * 16384 + 8192 + (wc * 64 + lo) * 64 + hi * 16;
    bf8_t af[4], bfr[4];
#pragma unroll
    for (int m = 0; m < 4; ++m) af[m] = *reinterpret_cast<const bf8_t*>(aRd + m * 1024);
#pragma unroll
    for (int n = 0; n < 4; ++n) bfr[n] = *reinterpret_cast<const bf8_t*>(bRd + n * 1024);
#pragma unroll
    for (int m = 0; m < 4; ++m)
#pragma unroll
      for (int n = 0; n < 4; ++n)
        acc[m][n] = __builtin_amdgcn_mfma_f32_16x16x32_bf16(af[m], bfr[n], acc[m][n], 0, 0, 0);

    // tile t+1 ready (4 oldest); tile t+2's 4 loads stay in flight
    if (t + 2 < NT) asm volatile("s_waitcnt vmcnt(4)" ::: "memory");
    else            asm volatile("s_waitcnt vmcnt(0)" ::: "memory");
    __builtin_amdgcn_s_barrier();
  }
#undef STAGE

  // epilogue: score = cnorm - 2*acc; C/D layout: col = lane&15, row = hi*4+j
  float cn[4];
#pragma unroll
  for (int n = 0; n < 4; ++n) cn[n] = cnorm[n0 + wc * 64 + n * 16 + lo];

#pragma unroll
  for (int m = 0; m < 4; ++m) {
#pragma unroll
    for (int j = 0; j < 4; ++j) {
      float m1 = INFINITY, m2 = INFINITY; int i1 = 0x7fffffff, i2 = 0x7fffffff;
#pragma unroll
      for (int n = 0; n < 4; ++n) {
        float s = fmaf(-2.f, acc[m][n][j], cn[n]);
        top2_push(s, n0 + wc * 64 + n * 16 + lo, m1, i1, m2, i2);
      }
      // reduce across the 16 lanes sharing this row (lo = 0..15)
#pragma unroll
      for (int mask = 1; mask <= 8; mask <<= 1) {
        float om1 = __shfl_xor(m1, mask, 64); int oi1 = __shfl_xor(i1, mask, 64);
        float om2 = __shfl_xor(m2, mask, 64); int oi2 = __shfl_xor(i2, mask, 64);
        top2_push(om1, oi1, m1, i1, m2, i2);
        top2_push(om2, oi2, m1, i1, m2, i2);
      }
      if (lo == 0) {
        int row = wr * 64 + m * 16 + hi * 4 + j;
        Top2 e; e.m1 = m1; e.i1 = i1; e.m2 = m2; e.i2 = i2;
        Ep[row][wc] = e;
      }
    }
  }
  __syncthreads();

  if (tid < BM) {
    Top2 a = Ep[tid][0], b = Ep[tid][1];
    float m1 = a.m1, m2 = a.m2; int i1 = a.i1, i2 = a.i2;
    top2_push(b.m1, b.i1, m1, i1, m2, i2);
    top2_push(b.m2, b.i2, m1, i1, m2, i2);
    Top2 r; r.m1 = m1; r.i1 = i1; r.m2 = m2; r.i2 = i2;
    part[(size_t)(m0 + tid) * NTILES + blockIdx.x] = r;
  }
}

// ---------------------------------------------------------------------------
// Kernel 3: merge 32 per-tile top-2 -> computed top-4; fp64-exact refine;
// gather winning code + positional encoding
// ---------------------------------------------------------------------------
__device__ __forceinline__ void ins4(float m, int i, float v[4], int ix[4]) {
  if (!(m < v[3] || (m == v[3] && i < ix[3]))) return;
  v[3] = m; ix[3] = i;
  if (v[3] < v[2] || (v[3] == v[2] && ix[3] < ix[2])) {
    float tv = v[2]; v[2] = v[3]; v[3] = tv; int ti = ix[2]; ix[2] = ix[3]; ix[3] = ti;
  }
  if (v[2] < v[1] || (v[2] == v[1] && ix[2] < ix[1])) {
    float tv = v[1]; v[1] = v[2]; v[2] = tv; int ti = ix[1]; ix[1] = ix[2]; ix[2] = ti;
  }
  if (v[1] < v[0] || (v[1] == v[0] && ix[1] < ix[0])) {
    float tv = v[0]; v[0] = v[1]; v[1] = tv; int ti = ix[0]; ix[0] = ix[1]; ix[1] = ti;
  }
}

__global__ void vq_finalize(const float* __restrict__ x, const float* __restrict__ cb,
                            const Top2* __restrict__ part, float* __restrict__ out) {
  const int t = blockIdx.x;
  const int s = t & (NS - 1);
  const int tid = threadIdx.x;
  const int lane = tid & 63;
  const int wav = tid >> 6;

  __shared__ int candS[4];
  __shared__ double dS[4];
  __shared__ int selS;

  if (wav == 0) {
    float v[4] = {INFINITY, INFINITY, INFINITY, INFINITY};
    int ix[4] = {0x7fffffff, 0x7fffffff, 0x7fffffff, 0x7fffffff};
    if (lane < NTILES) {
      Top2 e = part[(size_t)t * NTILES + lane];
      v[0] = e.m1; ix[0] = e.i1; v[1] = e.m2; ix[1] = e.i2;
    }
#pragma unroll
    for (int mask = 1; mask <= 16; mask <<= 1) {
      float ov[4]; int oi[4];
#pragma unroll
      for (int p = 0; p < 4; ++p) { ov[p] = __shfl_xor(v[p], mask, 64); oi[p] = __shfl_xor(ix[p], mask, 64); }
#pragma unroll
      for (int p = 0; p < 4; ++p) ins4(ov[p], oi[p], v, ix);
    }
    if (lane < 4) candS[lane] = ix[lane];
  }
  __syncthreads();

  // fp64-exact refine: wave w -> candidate w
  const int ci = candS[wav];
  const float* xt = x + (size_t)t * ND;
  const float* c = cb + (size_t)ci * ND;
  double d = 0.0;
#pragma unroll
  for (int r = 0; r < ND / 64; ++r) {
    int j = lane + 64 * r;
    double a = (double)xt[j] - (double)c[j];
    d = fma(a, a, d);
  }
#pragma unroll
  for (int off = 32; off > 0; off >>= 1) d += __shfl_down(d, off, 64);
  if (lane == 0) dS[wav] = d;
  __syncthreads();

  if (tid == 0) {
    double bd = dS[0]; int bi = candS[0];
#pragma unroll
    for (int w = 1; w < 4; ++w) {
      if (dS[w] < bd || (dS[w] == bd && candS[w] < bi)) { bd = dS[w]; bi = candS[w]; }
    }
    selS = bi;
  }
  __syncthreads();
  const int sel = selS;

  // gather + positional encoding
  const float coef = (float)(9.210340371976184 / 1024.0);  // ln(10000)/D
  const float* cs = cb + (size_t)sel * ND;
  float* ot = out + (size_t)t * ND;
  const float sf = (float)s;
#pragma unroll
  for (int r = 0; r < ND / 256; ++r) {
    int j = tid + 256 * r;
    int iv = j & ~1;
    float div = expf(-(float)iv * coef);
    float ang = sf * div;
    float pe = (j & 1) ? cosf(ang) : sinf(ang);
    ot[j] = cs[j] + pe;
  }
}

// ---------------------------------------------------------------------------
extern "C" void kernel_launch(void* const* d_in, const int* in_sizes, int n_in,
                              void* d_out, int out_size, void* d_ws, size_t ws_size,
                              hipStream_t stream) {
  const float* x = (const float*)d_in[0];     // [8,2048,1024] fp32
  const float* cb = (const float*)d_in[1];    // [4096,1024] fp32
  float* out = (float*)d_out;

  // workspace layout:
  // [0, 32MB)            x_bf16   (16,777,216 ushort)
  // [32MB, 40MB)         cb_bf16  (4,194,304 ushort)
  // [40MB, +16KB)        cnorm
  // [40MB+16KB, +8MB)    Top2 partials
  unsigned short* xb = (unsigned short*)d_ws;
  unsigned short* cbb = (unsigned short*)((char*)d_ws + (size_t)NM * ND * 2);
  float* cnorm = (float*)((char*)d_ws + (size_t)NM * ND * 2 + (size_t)NK * ND * 2);
  Top2* part = (Top2*)((char*)cnorm + 16384);

  vq_convert<<<2048, 256, 0, stream>>>(x, cb, xb, cbb);
  vq_cnorm<<<NK / 4, 256, 0, stream>>>(cb, cnorm);
  dim3 g2(NTILES, NM / BM);  // (32, 128)
  vq_dist_bf16<<<g2, 256, 0, stream>>>(xb, cbb, cnorm, part);
  vq_finalize<<<NM, 256, 0, stream>>>(x, cb, part, out);
}